// Round 2
// baseline (164.324 us; speedup 1.0000x reference)
//
#include <hip/hip_runtime.h>
#include <type_traits>
#include <stdint.h>

#define DEV __device__ __forceinline__

typedef float f32x4 __attribute__((ext_vector_type(4)));
typedef short bf16x8 __attribute__((ext_vector_type(8)));
typedef unsigned short u16;
typedef u16 u16x8 __attribute__((ext_vector_type(8)));

static constexpr int BTOT   = 65536;
static constexpr int NBLKB  = 64;            // B-chunk blocks
static constexpr int BSPAN  = BTOT / NBLKB;  // 1024
static constexpr int KB     = 64;            // batch per staged chunk
static constexpr int NCHUNK = BSPAN / KB;    // 16
static constexpr int NGEMM  = 9;
static constexpr int NRED   = 3;
static constexpr int NGRP   = NGEMM + NRED;  // 12
static constexpr int NG     = 56;            // true GEMM pairs
static constexpr int NCOL   = 45;            // 35 A-mono colsums + 10 x-mono colsums
static constexpr int MAXSLOT= 6;             // max staged monomial tiles per group
static constexpr float INVB = 1.0f / (float)BTOT;

struct GroupDesc {
  int np, na, nb, bsrc;       // pairs, A-monos, B-monos, B source (0:x1/x2, 1:y1/y2)
  int8_t aexp[4][4];          // A-mono exps over (s1,y1,s2,y2)
  int8_t bexp[4][2];          // B-mono exps over (x1,x2) or (y1,y2)
  int8_t pa[8], pb[8];        // pair -> LDS slot (pb already offset by na)
  int16_t gout[8];            // pair -> global G slot
};

struct Tables {
  int nW, nB, nM, nA, nX;
  int8_t expw[120][7];
  int8_t expb[20][3];
  int8_t expm[56][5];
  int8_t am[35][4];           // A-monomials (s1,y1,s2,y2), sum<=3, product order
  int8_t xm[10][2];           // 2-var monomials, sum<=3, product order
  GroupDesc grp[NGEMM];
  // combine-kernel term tables
  int8_t wtype[120]; int16_t widx[120]; int8_t wpow[120]; // 0:GEMM 1:colA[o] 2:colX[d]
  int8_t mtype[56];  int16_t midx[56];  int8_t mpow[56];  // 0:GEMM 1:colA[o] 2:colA[d]
  int16_t bcol[20];  int8_t bpow[20];
  int err, gcount;
};

constexpr int aidf(const Tables& t,int a,int b,int c,int d){
  for(int i=0;i<t.nA;i++)
    if(t.am[i][0]==a&&t.am[i][1]==b&&t.am[i][2]==c&&t.am[i][3]==d) return i;
  return -1;
}
constexpr int xidf(const Tables& t,int a,int b){
  for(int i=0;i<t.nX;i++) if(t.xm[i][0]==a&&t.xm[i][1]==b) return i;
  return -1;
}

constexpr Tables makeTables(){
  Tables t{};
  t.err = 0;
  // EXP_W (python product order, last index fastest)
  t.nW=0;
  for(int e0=0;e0<4;e0++)for(int e1=0;e1<4;e1++)for(int e2=0;e2<4;e2++)
  for(int e3=0;e3<4;e3++)for(int e4=0;e4<4;e4++)for(int e5=0;e5<4;e5++)
  for(int e6=0;e6<4;e6++) if(e0+e1+e2+e3+e4+e5+e6<=3){
    t.expw[t.nW][0]=(int8_t)e0; t.expw[t.nW][1]=(int8_t)e1; t.expw[t.nW][2]=(int8_t)e2;
    t.expw[t.nW][3]=(int8_t)e3; t.expw[t.nW][4]=(int8_t)e4; t.expw[t.nW][5]=(int8_t)e5;
    t.expw[t.nW][6]=(int8_t)e6; t.nW++;
  }
  // EXP_B
  t.nB=0;
  for(int e0=0;e0<4;e0++)for(int e1=0;e1<4;e1++)for(int e2=0;e2<4;e2++)
    if(e0+e1+e2<=3){ t.expb[t.nB][0]=(int8_t)e0; t.expb[t.nB][1]=(int8_t)e1; t.expb[t.nB][2]=(int8_t)e2; t.nB++; }
  // EXP_M
  t.nM=0;
  for(int e0=0;e0<4;e0++)for(int e1=0;e1<4;e1++)for(int e2=0;e2<4;e2++)
  for(int e3=0;e3<4;e3++)for(int e4=0;e4<4;e4++)
    if(e0+e1+e2+e3+e4<=3){
      t.expm[t.nM][0]=(int8_t)e0; t.expm[t.nM][1]=(int8_t)e1; t.expm[t.nM][2]=(int8_t)e2;
      t.expm[t.nM][3]=(int8_t)e3; t.expm[t.nM][4]=(int8_t)e4; t.nM++;
    }
  // A monomials
  t.nA=0;
  for(int a=0;a<4;a++)for(int b=0;b<4;b++)for(int c=0;c<4;c++)for(int d=0;d<4;d++)
    if(a+b+c+d<=3){ t.am[t.nA][0]=(int8_t)a; t.am[t.nA][1]=(int8_t)b; t.am[t.nA][2]=(int8_t)c; t.am[t.nA][3]=(int8_t)d; t.nA++; }
  // 2-var monomials
  t.nX=0;
  for(int a=0;a<4;a++)for(int b=0;b<4;b++)
    if(a+b<=3){ t.xm[t.nX][0]=(int8_t)a; t.xm[t.nX][1]=(int8_t)b; t.nX++; }

  // degree lists
  int vd1[4]={0,0,0,0}; int vd2[10]={0,0,0,0,0,0,0,0,0,0}; int n1=0,n2=0;
  for(int i=0;i<t.nA;i++){
    int dg=t.am[i][0]+t.am[i][1]+t.am[i][2]+t.am[i][3];
    if(dg==1) vd1[n1++]=i; else if(dg==2) vd2[n2++]=i;
  }
  int xd1[2]={0,0}; int xd2[3]={0,0,0}; int m1=0,m2=0;
  for(int i=0;i<t.nX;i++){
    int dg=t.xm[i][0]+t.xm[i][1];
    if(dg==1) xd1[m1++]=i; else if(dg==2) xd2[m2++]=i;
  }
  if(n1!=4||n2!=10||m1!=2||m2!=3) t.err+=1;

  int wslot[35][10]; int mslot[10][10];
  for(int i=0;i<35;i++)for(int j=0;j<10;j++) wslot[i][j]=-1;
  for(int i=0;i<10;i++)for(int j=0;j<10;j++) mslot[i][j]=-1;

  int slot=0;
  // G0,G1: 2 deg-1 v's x {xd1[0],xd1[1],xd2[0],xd2[1]}
  for(int gi=0; gi<2; gi++){
    GroupDesc& g=t.grp[gi];
    g.bsrc=0; g.na=2; g.nb=4; g.np=8;
    int av[2]={vd1[gi*2],vd1[gi*2+1]};
    int bv[4]={xd1[0],xd1[1],xd2[0],xd2[1]};
    for(int k=0;k<2;k++)for(int q=0;q<4;q++) g.aexp[k][q]=t.am[av[k]][q];
    for(int k=0;k<4;k++){ g.bexp[k][0]=t.xm[bv[k]][0]; g.bexp[k][1]=t.xm[bv[k]][1]; }
    int p=0;
    for(int i=0;i<2;i++)for(int j=0;j<4;j++){
      g.pa[p]=(int8_t)i; g.pb[p]=(int8_t)(g.na+j); g.gout[p]=(int16_t)slot;
      wslot[av[i]][bv[j]]=slot; slot++; p++;
    }
  }
  // G2: 4 deg-1 v's x xd2[2]
  {
    GroupDesc& g=t.grp[2]; g.bsrc=0; g.na=4; g.nb=1; g.np=4;
    for(int k=0;k<4;k++)for(int q=0;q<4;q++) g.aexp[k][q]=t.am[vd1[k]][q];
    g.bexp[0][0]=t.xm[xd2[2]][0]; g.bexp[0][1]=t.xm[xd2[2]][1];
    for(int i=0;i<4;i++){
      g.pa[i]=(int8_t)i; g.pb[i]=(int8_t)g.na; g.gout[i]=(int16_t)slot;
      wslot[vd1[i]][xd2[2]]=slot; slot++;
    }
  }
  // G3,G4: 4 deg-2 v's x {xd1[0],xd1[1]}
  for(int gi=3; gi<=4; gi++){
    GroupDesc& g=t.grp[gi]; g.bsrc=0; g.na=4; g.nb=2; g.np=8;
    int base=(gi-3)*4;
    for(int k=0;k<4;k++)for(int q=0;q<4;q++) g.aexp[k][q]=t.am[vd2[base+k]][q];
    for(int k=0;k<2;k++){ g.bexp[k][0]=t.xm[xd1[k]][0]; g.bexp[k][1]=t.xm[xd1[k]][1]; }
    int p=0;
    for(int i=0;i<4;i++)for(int j=0;j<2;j++){
      g.pa[p]=(int8_t)i; g.pb[p]=(int8_t)(g.na+j); g.gout[p]=(int16_t)slot;
      wslot[vd2[base+i]][xd1[j]]=slot; slot++; p++;
    }
  }
  // G5: last 2 deg-2 v's x {xd1}
  {
    GroupDesc& g=t.grp[5]; g.bsrc=0; g.na=2; g.nb=2; g.np=4;
    for(int k=0;k<2;k++)for(int q=0;q<4;q++) g.aexp[k][q]=t.am[vd2[8+k]][q];
    for(int k=0;k<2;k++){ g.bexp[k][0]=t.xm[xd1[k]][0]; g.bexp[k][1]=t.xm[xd1[k]][1]; }
    int p=0;
    for(int i=0;i<2;i++)for(int j=0;j<2;j++){
      g.pa[p]=(int8_t)i; g.pb[p]=(int8_t)(g.na+j); g.gout[p]=(int16_t)slot;
      wslot[vd2[8+i]][xd1[j]]=slot; slot++; p++;
    }
  }
  // G6 (m): lefts deg1 x rights {xd1[0],xd1[1],xd2[0],xd2[1]}  (src = y1,y2)
  {
    GroupDesc& g=t.grp[6]; g.bsrc=1; g.na=2; g.nb=4; g.np=8;
    for(int k=0;k<2;k++){ g.aexp[k][0]=0; g.aexp[k][1]=t.xm[xd1[k]][0]; g.aexp[k][2]=0; g.aexp[k][3]=t.xm[xd1[k]][1]; }
    int bv[4]={xd1[0],xd1[1],xd2[0],xd2[1]};
    for(int k=0;k<4;k++){ g.bexp[k][0]=t.xm[bv[k]][0]; g.bexp[k][1]=t.xm[bv[k]][1]; }
    int p=0;
    for(int i=0;i<2;i++)for(int j=0;j<4;j++){
      g.pa[p]=(int8_t)i; g.pb[p]=(int8_t)(g.na+j); g.gout[p]=(int16_t)slot;
      mslot[xd1[i]][bv[j]]=slot; slot++; p++;
    }
  }
  // G7 (m): lefts deg2 (3) x rights deg1 (2)
  {
    GroupDesc& g=t.grp[7]; g.bsrc=1; g.na=3; g.nb=2; g.np=6;
    for(int k=0;k<3;k++){ g.aexp[k][0]=0; g.aexp[k][1]=t.xm[xd2[k]][0]; g.aexp[k][2]=0; g.aexp[k][3]=t.xm[xd2[k]][1]; }
    for(int k=0;k<2;k++){ g.bexp[k][0]=t.xm[xd1[k]][0]; g.bexp[k][1]=t.xm[xd1[k]][1]; }
    int p=0;
    for(int i=0;i<3;i++)for(int j=0;j<2;j++){
      g.pa[p]=(int8_t)i; g.pb[p]=(int8_t)(g.na+j); g.gout[p]=(int16_t)slot;
      mslot[xd2[i]][xd1[j]]=slot; slot++; p++;
    }
  }
  // G8 (m): lefts deg1 (2) x right xd2[2]
  {
    GroupDesc& g=t.grp[8]; g.bsrc=1; g.na=2; g.nb=1; g.np=2;
    for(int k=0;k<2;k++){ g.aexp[k][0]=0; g.aexp[k][1]=t.xm[xd1[k]][0]; g.aexp[k][2]=0; g.aexp[k][3]=t.xm[xd1[k]][1]; }
    g.bexp[0][0]=t.xm[xd2[2]][0]; g.bexp[0][1]=t.xm[xd2[2]][1];
    for(int i=0;i<2;i++){
      g.pa[i]=(int8_t)i; g.pb[i]=(int8_t)g.na; g.gout[i]=(int16_t)slot;
      mslot[xd1[i]][xd2[2]]=slot; slot++;
    }
  }
  t.gcount=slot;
  if(slot!=NG) t.err+=1;

  // combine tables: delta_w
  for(int i=0;i<t.nW;i++){
    const int8_t* e=t.expw[i];
    bool u0=(e[0]==0&&e[3]==0);
    bool v0=(e[1]==0&&e[2]==0&&e[4]==0&&e[5]==0);
    t.wpow[i]=e[6];
    if(u0){ t.wtype[i]=1; t.widx[i]=(int16_t)aidf(t,e[1],e[2],e[4],e[5]); }
    else if(v0){ t.wtype[i]=2; t.widx[i]=(int16_t)xidf(t,e[0],e[3]); }
    else {
      int s=wslot[aidf(t,e[1],e[2],e[4],e[5])][xidf(t,e[0],e[3])];
      if(s<0) t.err+=1;
      t.wtype[i]=0; t.widx[i]=(int16_t)s;
    }
  }
  // delta_m: left=(e1,e3), right=(e0,e2)
  for(int i=0;i<t.nM;i++){
    const int8_t* e=t.expm[i];
    bool L0=(e[1]==0&&e[3]==0), R0=(e[0]==0&&e[2]==0);
    t.mpow[i]=e[4];
    if(L0){ t.mtype[i]=2; t.midx[i]=(int16_t)aidf(t,0,e[0],0,e[2]); }       // colsum(right)[d]
    else if(R0){ t.mtype[i]=1; t.midx[i]=(int16_t)aidf(t,0,e[1],0,e[3]); }  // colsum(left)[o]
    else {
      int s=mslot[xidf(t,e[1],e[3])][xidf(t,e[0],e[2])];
      if(s<0) t.err+=1;
      t.mtype[i]=0; t.midx[i]=(int16_t)s;
    }
  }
  // delta_b
  for(int i=0;i<t.nB;i++){
    const int8_t* e=t.expb[i];
    t.bcol[i]=(int16_t)aidf(t,0,e[0],0,e[1]); t.bpow[i]=e[2];
  }
  return t;
}

constexpr Tables TB = makeTables();
static_assert(TB.err==0 && TB.gcount==56, "table build failed");
static_assert(TB.nW==120 && TB.nB==20 && TB.nM==56 && TB.nA==35 && TB.nX==10, "enumeration mismatch");

// ---- helpers ----
template<int N, typename F>
DEV void sunroll(F&& f){
  if constexpr (N > 0){
    sunroll<N-1>(static_cast<F&&>(f));
    f(std::integral_constant<int, N-1>{});
  }
}
template<int E> DEV float ipw(float x){
  if constexpr(E==0) return 1.0f;
  else if constexpr(E==1) return x;
  else if constexpr(E==2) return x*x;
  else return x*x*x;
}
DEV u16 f2bf(float f){
  uint32_t u = __builtin_bit_cast(uint32_t, f);
  u = u + 0x7FFFu + ((u>>16)&1u);
  return (u16)(u>>16);
}
constexpr bool needAvar(int gi,int v){
  for(int k=0;k<TB.grp[gi].na;k++) if(TB.grp[gi].aexp[k][v]>0) return true;
  return false;
}
constexpr bool needBvar(int gi,int v){
  for(int k=0;k<TB.grp[gi].nb;k++) if(TB.grp[gi].bexp[k][v]>0) return true;
  return false;
}
constexpr bool redNeed(int ri,int v){
  for(int k=0;k<15;k++){
    int s=ri*15+k;
    if(s<35){ if(v<4 && TB.am[s][v]>0) return true; }
    else    { if(v>=4 && TB.xm[s-35][v-4]>0) return true; }
  }
  return false;
}

// ---- main GEMM group: stages monomial tiles in MFMA-fragment order, per-wave 64x64 pair ----
template<int GI>
DEV void gemmGroup(const float* __restrict__ s1,const float* __restrict__ y1,
                   const float* __restrict__ s2,const float* __restrict__ y2,
                   const float* __restrict__ x1,const float* __restrict__ x2,
                   float* __restrict__ G, u16* lds, int tid, int by)
{
  constexpr int NA = TB.grp[GI].na;
  constexpr int NB = TB.grp[GI].nb;
  constexpr int NP = TB.grp[GI].np;
  constexpr int BS = TB.grp[GI].bsrc;
  constexpr bool bx0 = needBvar(GI,0), bx1 = needBvar(GI,1);
  constexpr bool ld_s1 = needAvar(GI,0);
  constexpr bool ld_y1 = needAvar(GI,1) || (BS==1 && bx0);
  constexpr bool ld_s2 = needAvar(GI,2);
  constexpr bool ld_y2 = needAvar(GI,3) || (BS==1 && bx1);
  constexpr bool ld_x1 = (BS==0) && bx0;
  constexpr bool ld_x2 = (BS==0) && bx1;

  const int w = tid>>6, l = tid&63;
  const int sub = tid>>8, ob = (tid>>6)&3;
  const int ch  = ob*16 + (l&15);
  const int bro = sub*32 + 8*(l>>4);
  const int base = by*BSPAN;

  f32x4 acc[4][4] = {};

  int aslot=0, bslot=0, gsl=0;
  if (w < NP){
    sunroll<NP>([&](auto PP){
      constexpr int p = decltype(PP)::value;
      if (w==p){ aslot=TB.grp[GI].pa[p]; bslot=TB.grp[GI].pb[p]; gsl=TB.grp[GI].gout[p]; }
    });
  }

  for(int ck=0; ck<NCHUNK; ++ck){
    const int b0 = base + ck*KB + bro;
    float A0[8]={},A1[8]={},A2[8]={},A3[8]={},Bx0[8]={},Bx1[8]={};
    #pragma unroll
    for(int j=0;j<8;j++){
      const int off = (b0+j)*64 + ch;
      if constexpr(ld_s1) A0[j]=s1[off];
      if constexpr(ld_y1) A1[j]=y1[off];
      if constexpr(ld_s2) A2[j]=s2[off];
      if constexpr(ld_y2) A3[j]=y2[off];
      if constexpr(ld_x1) Bx0[j]=x1[off];
      if constexpr(ld_x2) Bx1[j]=x2[off];
    }
    // A-monomials -> slots [0,NA)
    sunroll<NA>([&](auto KK){
      constexpr int k = decltype(KK)::value;
      constexpr int e0=TB.grp[GI].aexp[k][0];
      constexpr int e1=TB.grp[GI].aexp[k][1];
      constexpr int e2=TB.grp[GI].aexp[k][2];
      constexpr int e3=TB.grp[GI].aexp[k][3];
      u16x8 o8;
      #pragma unroll
      for(int j=0;j<8;j++){
        float v = ipw<e0>(A0[j]);
        v *= ipw<e1>(A1[j]);
        v *= ipw<e2>(A2[j]);
        v *= ipw<e3>(A3[j]);
        o8[j]=f2bf(v);
      }
      *(u16x8*)&lds[(k*512 + tid)*8] = o8;
    });
    // B-monomials -> slots [NA, NA+NB)
    sunroll<NB>([&](auto KK){
      constexpr int k = decltype(KK)::value;
      constexpr int q0=TB.grp[GI].bexp[k][0];
      constexpr int q1=TB.grp[GI].bexp[k][1];
      u16x8 o8;
      #pragma unroll
      for(int j=0;j<8;j++){
        float v0 = (BS==1)? A1[j] : Bx0[j];
        float v1 = (BS==1)? A3[j] : Bx1[j];
        float v = ipw<q0>(v0)*ipw<q1>(v1);
        o8[j]=f2bf(v);
      }
      *(u16x8*)&lds[((NA+k)*512 + tid)*8] = o8;
    });
    __syncthreads();
    if (w < NP){
      #pragma unroll
      for(int sb=0; sb<2; ++sb){
        bf16x8 Af[4];
        #pragma unroll
        for(int o2=0;o2<4;o2++)
          Af[o2] = *(const bf16x8*)&lds[(aslot*512 + sb*256 + o2*64 + l)*8];
        #pragma unroll
        for(int db=0;db<4;db++){
          bf16x8 Bf = *(const bf16x8*)&lds[(bslot*512 + sb*256 + db*64 + l)*8];
          #pragma unroll
          for(int o2=0;o2<4;o2++)
            acc[o2][db] = __builtin_amdgcn_mfma_f32_16x16x32_bf16(Af[o2], Bf, acc[o2][db], 0, 0, 0);
        }
      }
    }
    __syncthreads();
  }
  if (w < NP){
    float* dst = G + gsl*4096;
    const int r0=(l>>4)*4, cc=l&15;   // verified C/D layout: col=lane&15, row=(lane>>4)*4+reg
    #pragma unroll
    for(int o2=0;o2<4;o2++)
      #pragma unroll
      for(int db=0;db<4;db++)
        #pragma unroll
        for(int r=0;r<4;r++)
          atomicAdd(&dst[(o2*16+r0+r)*64 + db*16+cc], acc[o2][db][r]);
  }
}

// ---- reduction groups: 45 column sums in fp32 ----
template<int RI>
DEV void reduceGroup(const float* __restrict__ s1,const float* __restrict__ y1,
                     const float* __restrict__ s2,const float* __restrict__ y2,
                     const float* __restrict__ x1,const float* __restrict__ x2,
                     float* __restrict__ col, float* ldsF, int tid, int by)
{
  constexpr int RB = RI*15;
  constexpr bool f0=redNeed(RI,0), f1=redNeed(RI,1), f2=redNeed(RI,2), f3=redNeed(RI,3),
                 f4=redNeed(RI,4), f5=redNeed(RI,5);
  float acc[15] = {};
  const int ch = tid&63, wv = tid>>6;
  const int base = by*BSPAN;
  for(int r=wv; r<BSPAN; r+=8){
    const int off = (base+r)*64 + ch;
    float vs1=0,vy1=0,vs2=0,vy2=0,vx1=0,vx2=0;
    if constexpr(f0) vs1=s1[off];
    if constexpr(f1) vy1=y1[off];
    if constexpr(f2) vs2=s2[off];
    if constexpr(f3) vy2=y2[off];
    if constexpr(f4) vx1=x1[off];
    if constexpr(f5) vx2=x2[off];
    sunroll<15>([&](auto KK){
      constexpr int k = decltype(KK)::value;
      constexpr int s = RB + k;
      float v;
      if constexpr(s < 35){
        v = ipw<TB.am[s][0]>(vs1) * ipw<TB.am[s][1]>(vy1) * ipw<TB.am[s][2]>(vs2) * ipw<TB.am[s][3]>(vy2);
      } else {
        v = ipw<TB.xm[s-35][0]>(vx1) * ipw<TB.xm[s-35][1]>(vx2);
      }
      acc[k] += v;
    });
  }
  sunroll<15>([&](auto KK){
    constexpr int k = decltype(KK)::value;
    ldsF[(k*8 + wv)*64 + ch] = acc[k];
  });
  __syncthreads();
  for(int idx=tid; idx<15*64; idx+=512){
    const int k=idx>>6, c=idx&63;
    float s=0.f;
    #pragma unroll
    for(int q=0;q<8;q++) s += ldsF[(k*8+q)*64 + c];
    atomicAdd(&col[(RB+k)*64 + c], s);
  }
}

__global__ __launch_bounds__(512) void k_main(
    const float* __restrict__ x1, const float* __restrict__ s1, const float* __restrict__ y1,
    const float* __restrict__ x2, const float* __restrict__ s2, const float* __restrict__ y2,
    float* __restrict__ G, float* __restrict__ col)
{
  __shared__ u16 lds[MAXSLOT*512*8];   // 48 KiB
  const int tid = threadIdx.x, by = blockIdx.y;
  switch(blockIdx.x){
    case 0: gemmGroup<0>(s1,y1,s2,y2,x1,x2,G,lds,tid,by); break;
    case 1: gemmGroup<1>(s1,y1,s2,y2,x1,x2,G,lds,tid,by); break;
    case 2: gemmGroup<2>(s1,y1,s2,y2,x1,x2,G,lds,tid,by); break;
    case 3: gemmGroup<3>(s1,y1,s2,y2,x1,x2,G,lds,tid,by); break;
    case 4: gemmGroup<4>(s1,y1,s2,y2,x1,x2,G,lds,tid,by); break;
    case 5: gemmGroup<5>(s1,y1,s2,y2,x1,x2,G,lds,tid,by); break;
    case 6: gemmGroup<6>(s1,y1,s2,y2,x1,x2,G,lds,tid,by); break;
    case 7: gemmGroup<7>(s1,y1,s2,y2,x1,x2,G,lds,tid,by); break;
    case 8: gemmGroup<8>(s1,y1,s2,y2,x1,x2,G,lds,tid,by); break;
    case 9:  reduceGroup<0>(s1,y1,s2,y2,x1,x2,col,(float*)lds,tid,by); break;
    case 10: reduceGroup<1>(s1,y1,s2,y2,x1,x2,col,(float*)lds,tid,by); break;
    default: reduceGroup<2>(s1,y1,s2,y2,x1,x2,col,(float*)lds,tid,by); break;
  }
}

__global__ __launch_bounds__(256) void k_combine(
    const float* __restrict__ G, const float* __restrict__ col,
    const float* __restrict__ w, const float* __restrict__ b, const float* __restrict__ m,
    const float* __restrict__ parw, const float* __restrict__ parb, const float* __restrict__ parm,
    float* __restrict__ out)
{
  const int n = blockIdx.x*256 + threadIdx.x;   // 0..4095
  const int o = n>>6, d = n&63;
  const float wv = w[n], mv = m[n];
  const float wp[4] = {1.f, wv, wv*wv, wv*wv*wv};
  const float mp[4] = {1.f, mv, mv*mv, mv*mv*mv};
  float aw=0.f, am=0.f;
  sunroll<120>([&](auto II){
    constexpr int i = decltype(II)::value;
    constexpr int ty = TB.wtype[i];
    constexpr int ix = TB.widx[i];
    constexpr int q  = TB.wpow[i];
    float val;
    if constexpr(ty==0) val = G[ix*4096 + n];
    else if constexpr(ty==1) val = col[ix*64 + o];
    else val = col[(35+ix)*64 + d];
    aw += parw[i] * val * wp[q];
  });
  sunroll<56>([&](auto II){
    constexpr int i = decltype(II)::value;
    constexpr int ty = TB.mtype[i];
    constexpr int ix = TB.midx[i];
    constexpr int q  = TB.mpow[i];
    float val;
    if constexpr(ty==0) val = G[ix*4096 + n];
    else if constexpr(ty==1) val = col[ix*64 + o];
    else val = col[ix*64 + d];
    am += parm[i] * val * mp[q];
  });
  aw *= INVB; am *= INVB;
  if (o==d) am += parm[56];
  out[n] = aw;
  out[4160 + n] = am;
  if (n < 64){
    const float bv = b[n];
    const float bp[4] = {1.f, bv, bv*bv, bv*bv*bv};
    float ab=0.f;
    sunroll<20>([&](auto II){
      constexpr int i = decltype(II)::value;
      constexpr int cix = TB.bcol[i];
      constexpr int q = TB.bpow[i];
      ab += parb[i] * col[cix*64 + n] * bp[q];
    });
    out[4096 + n] = ab * INVB;
  }
}

extern "C" void kernel_launch(void* const* d_in, const int* in_sizes, int n_in,
                              void* d_out, int out_size, void* d_ws, size_t ws_size,
                              hipStream_t stream)
{
  const float* x1=(const float*)d_in[0];
  const float* s1=(const float*)d_in[1];
  const float* y1=(const float*)d_in[2];
  const float* x2=(const float*)d_in[3];
  const float* s2=(const float*)d_in[4];
  const float* y2=(const float*)d_in[5];
  const float* w =(const float*)d_in[6];
  const float* b =(const float*)d_in[7];
  const float* m =(const float*)d_in[8];
  const float* parw=(const float*)d_in[9];
  const float* parb=(const float*)d_in[10];
  const float* parm=(const float*)d_in[11];

  float* G   = (float*)d_ws;
  float* col = G + NG*4096;

  hipMemsetAsync(d_ws, 0, (size_t)(NG*4096 + NCOL*64)*sizeof(float), stream);
  k_main<<<dim3(NGRP, NBLKB), 512, 0, stream>>>(x1,s1,y1,x2,s2,y2,G,col);
  k_combine<<<16, 256, 0, stream>>>(G,col,w,b,m,parw,parb,parm,(float*)d_out);
}

// Round 3
// 123.925 us; speedup vs baseline: 1.3260x; 1.3260x over previous
//
#include <hip/hip_runtime.h>
#include <type_traits>
#include <stdint.h>

#define DEV __device__ __forceinline__

typedef float f32x4 __attribute__((ext_vector_type(4)));
typedef short bf16x8 __attribute__((ext_vector_type(8)));
typedef unsigned short u16;
typedef u16 u16x4 __attribute__((ext_vector_type(4)));

static constexpr int BTOT = 65536;
static constexpr int KB   = 64;
static constexpr int NCHT = BTOT / KB;      // 1024 total chunks
static constexpr int NG   = 56;             // true GEMM pairs
static constexpr int NCOLSUM = 45;
static constexpr float INVB = 1.0f / (float)BTOT;

// column block counts (byte-balanced: chunks/block x arrays ~= const)
static constexpr int NBLK_M  = 48;
static constexpr int NBLK_W1 = 96;
static constexpr int NBLK_W2 = 96;
static constexpr int NBLK_W3 = 128;
static constexpr int NBLK_R  = 144;
static constexpr int GRID    = NBLK_M+NBLK_W1+NBLK_W2+NBLK_W3+NBLK_R; // 512
static constexpr int THR_M  = NBLK_M;
static constexpr int THR_W1 = THR_M + NBLK_W1;
static constexpr int THR_W2 = THR_W1 + NBLK_W2;
static constexpr int THR_W3 = THR_W2 + NBLK_W3;

struct Col {
  int nslot, np, nsplit, nb;
  int8_t sexp[10][6];          // slot exps over (s1,y1,s2,y2,x1,x2)
  int8_t pa[16], pb[16];       // pair -> slot indices
  int16_t gout[16];            // pair -> global G slot
  uint8_t ldmask;              // which arrays to load
};

struct Tables {
  int nW, nB, nM, nA, nX;
  int8_t expw[120][7];
  int8_t expb[20][3];
  int8_t expm[56][5];
  int8_t am[35][4];            // 4-var monos (s1,y1,s2,y2), product order
  int8_t xm[10][2];            // 2-var monos, product order
  Col col[4];
  // combine-kernel term tables
  int8_t wtype[120]; int16_t widx[120]; int8_t wpow[120]; // 0:GEMM 1:colA[o] 2:colX[d]
  int8_t mtype[56];  int16_t midx[56];  int8_t mpow[56];  // 0:GEMM 1:colA[o] 2:colA[d]
  int16_t bcol[20];  int8_t bpow[20];
  int err, gcount;
};

constexpr int aidf(const Tables& t,int a,int b,int c,int d){
  for(int i=0;i<t.nA;i++)
    if(t.am[i][0]==a&&t.am[i][1]==b&&t.am[i][2]==c&&t.am[i][3]==d) return i;
  return -1;
}
constexpr int xidf(const Tables& t,int a,int b){
  for(int i=0;i<t.nX;i++) if(t.xm[i][0]==a&&t.xm[i][1]==b) return i;
  return -1;
}

constexpr Tables makeTables(){
  Tables t{};
  t.err = 0;
  // EXP_W (python product order)
  t.nW=0;
  for(int e0=0;e0<4;e0++)for(int e1=0;e1<4;e1++)for(int e2=0;e2<4;e2++)
  for(int e3=0;e3<4;e3++)for(int e4=0;e4<4;e4++)for(int e5=0;e5<4;e5++)
  for(int e6=0;e6<4;e6++) if(e0+e1+e2+e3+e4+e5+e6<=3){
    t.expw[t.nW][0]=(int8_t)e0; t.expw[t.nW][1]=(int8_t)e1; t.expw[t.nW][2]=(int8_t)e2;
    t.expw[t.nW][3]=(int8_t)e3; t.expw[t.nW][4]=(int8_t)e4; t.expw[t.nW][5]=(int8_t)e5;
    t.expw[t.nW][6]=(int8_t)e6; t.nW++;
  }
  t.nB=0;
  for(int e0=0;e0<4;e0++)for(int e1=0;e1<4;e1++)for(int e2=0;e2<4;e2++)
    if(e0+e1+e2<=3){ t.expb[t.nB][0]=(int8_t)e0; t.expb[t.nB][1]=(int8_t)e1; t.expb[t.nB][2]=(int8_t)e2; t.nB++; }
  t.nM=0;
  for(int e0=0;e0<4;e0++)for(int e1=0;e1<4;e1++)for(int e2=0;e2<4;e2++)
  for(int e3=0;e3<4;e3++)for(int e4=0;e4<4;e4++)
    if(e0+e1+e2+e3+e4<=3){
      t.expm[t.nM][0]=(int8_t)e0; t.expm[t.nM][1]=(int8_t)e1; t.expm[t.nM][2]=(int8_t)e2;
      t.expm[t.nM][3]=(int8_t)e3; t.expm[t.nM][4]=(int8_t)e4; t.nM++;
    }
  t.nA=0;
  for(int a=0;a<4;a++)for(int b=0;b<4;b++)for(int c=0;c<4;c++)for(int d=0;d<4;d++)
    if(a+b+c+d<=3){ t.am[t.nA][0]=(int8_t)a; t.am[t.nA][1]=(int8_t)b; t.am[t.nA][2]=(int8_t)c; t.am[t.nA][3]=(int8_t)d; t.nA++; }
  t.nX=0;
  for(int a=0;a<4;a++)for(int b=0;b<4;b++)
    if(a+b<=3){ t.xm[t.nX][0]=(int8_t)a; t.xm[t.nX][1]=(int8_t)b; t.nX++; }

  int wslot[35][10]; int mslot[10][10];
  for(int i=0;i<35;i++)for(int j=0;j<10;j++) wslot[i][j]=-1;
  for(int i=0;i<10;i++)for(int j=0;j<10;j++) mslot[i][j]=-1;

  int slot=0;

  // --- Col 0: M (y-monos of (y1,y2), shared A/B slot set) ---
  {
    Col& c = t.col[0]; c.nslot=5; c.nsplit=1; c.nb=NBLK_M;
    int ye[5][2] = {{0,1},{1,0},{0,2},{1,1},{2,0}};   // (y1e,y2e): y2,y1,y2^2,y1y2,y1^2
    int xmid[5] = {0,0,0,0,0};
    for(int s=0;s<5;s++){
      c.sexp[s][0]=0; c.sexp[s][1]=(int8_t)ye[s][0]; c.sexp[s][2]=0;
      c.sexp[s][3]=(int8_t)ye[s][1]; c.sexp[s][4]=0; c.sexp[s][5]=0;
      xmid[s]=xidf(t, ye[s][0], ye[s][1]);
      if(xmid[s]<0) t.err+=1;
    }
    int p=0;
    for(int L=0;L<2;L++)for(int R=0;R<5;R++){
      c.pa[p]=(int8_t)L; c.pb[p]=(int8_t)R; c.gout[p]=(int16_t)slot;
      mslot[xmid[L]][xmid[R]]=slot; slot++; p++;
    }
    for(int L=2;L<5;L++)for(int R=0;R<2;R++){
      c.pa[p]=(int8_t)L; c.pb[p]=(int8_t)R; c.gout[p]=(int16_t)slot;
      mslot[xmid[L]][xmid[R]]=slot; slot++; p++;
    }
    c.np=p;
    if(p!=16) t.err+=1;
  }
  // --- Col 1/2: W1 (s1,y1) and W2 (s2,y2) ---
  for(int wc=0; wc<2; wc++){
    Col& c = t.col[1+wc]; c.nslot=10; c.nsplit=1; c.nb = wc? NBLK_W2 : NBLK_W1;
    int ae[5][2] = {{1,0},{0,1},{2,0},{1,1},{0,2}};   // (v0e,v1e): v0,v1,v0^2,v0v1,v1^2
    int xe[5][2] = {{0,1},{1,0},{0,2},{1,1},{2,0}};   // (x1e,x2e)
    int amid[5]={0,0,0,0,0}, xmidb[5]={0,0,0,0,0};
    for(int s=0;s<5;s++){
      for(int q=0;q<6;q++) c.sexp[s][q]=0;
      if(wc==0){ c.sexp[s][0]=(int8_t)ae[s][0]; c.sexp[s][1]=(int8_t)ae[s][1];
                 amid[s]=aidf(t, ae[s][0], ae[s][1], 0, 0); }
      else     { c.sexp[s][2]=(int8_t)ae[s][0]; c.sexp[s][3]=(int8_t)ae[s][1];
                 amid[s]=aidf(t, 0, 0, ae[s][0], ae[s][1]); }
      if(amid[s]<0) t.err+=1;
      for(int q=0;q<6;q++) c.sexp[5+s][q]=0;
      c.sexp[5+s][4]=(int8_t)xe[s][0]; c.sexp[5+s][5]=(int8_t)xe[s][1];
      xmidb[s]=xidf(t, xe[s][0], xe[s][1]);
      if(xmidb[s]<0) t.err+=1;
    }
    int p=0;
    for(int a=0;a<2;a++)for(int b=0;b<5;b++){
      c.pa[p]=(int8_t)a; c.pb[p]=(int8_t)(5+b); c.gout[p]=(int16_t)slot;
      wslot[amid[a]][xmidb[b]]=slot; slot++; p++;
    }
    for(int a=2;a<5;a++)for(int b=0;b<2;b++){
      c.pa[p]=(int8_t)a; c.pb[p]=(int8_t)(5+b); c.gout[p]=(int16_t)slot;
      wslot[amid[a]][xmidb[b]]=slot; slot++; p++;
    }
    c.np=p;
    if(p!=16) t.err+=1;
  }
  // --- Col 3: W3 (mixed deg-2 v's x deg-1 u's), N-split 2 ---
  {
    Col& c = t.col[3]; c.nslot=6; c.nsplit=2; c.nb=NBLK_W3;
    int ae4[4][4] = {{1,0,1,0},{1,0,0,1},{0,1,1,0},{0,1,0,1}};
    int xe[2][2] = {{0,1},{1,0}};
    int amid[4]={0,0,0,0}, xmidb[2]={0,0};
    for(int s=0;s<4;s++){
      c.sexp[s][0]=(int8_t)ae4[s][0]; c.sexp[s][1]=(int8_t)ae4[s][1];
      c.sexp[s][2]=(int8_t)ae4[s][2]; c.sexp[s][3]=(int8_t)ae4[s][3];
      c.sexp[s][4]=0; c.sexp[s][5]=0;
      amid[s]=aidf(t, ae4[s][0], ae4[s][1], ae4[s][2], ae4[s][3]);
      if(amid[s]<0) t.err+=1;
    }
    for(int s=0;s<2;s++){
      for(int q=0;q<6;q++) c.sexp[4+s][q]=0;
      c.sexp[4+s][4]=(int8_t)xe[s][0]; c.sexp[4+s][5]=(int8_t)xe[s][1];
      xmidb[s]=xidf(t, xe[s][0], xe[s][1]);
      if(xmidb[s]<0) t.err+=1;
    }
    int p=0;
    for(int a=0;a<4;a++)for(int b=0;b<2;b++){
      c.pa[p]=(int8_t)a; c.pb[p]=(int8_t)(4+b); c.gout[p]=(int16_t)slot;
      wslot[amid[a]][xmidb[b]]=slot; slot++; p++;
    }
    c.np=p;
    if(p!=8) t.err+=1;
  }
  t.gcount=slot;
  if(slot!=NG) t.err+=1;

  // ldmask from slot exps
  for(int ci=0; ci<4; ci++){
    unsigned m=0;
    for(int s=0;s<t.col[ci].nslot;s++)
      for(int v=0;v<6;v++) if(t.col[ci].sexp[s][v]>0) m |= (1u<<v);
    t.col[ci].ldmask=(uint8_t)m;
  }

  // --- combine tables (same logic as verified baseline) ---
  for(int i=0;i<t.nW;i++){
    const int8_t* e=t.expw[i];
    bool u0=(e[0]==0&&e[3]==0);
    bool v0=(e[1]==0&&e[2]==0&&e[4]==0&&e[5]==0);
    t.wpow[i]=e[6];
    if(u0){ t.wtype[i]=1; t.widx[i]=(int16_t)aidf(t,e[1],e[2],e[4],e[5]); }
    else if(v0){ t.wtype[i]=2; t.widx[i]=(int16_t)xidf(t,e[0],e[3]); }
    else {
      int s=wslot[aidf(t,e[1],e[2],e[4],e[5])][xidf(t,e[0],e[3])];
      if(s<0) t.err+=1;
      t.wtype[i]=0; t.widx[i]=(int16_t)s;
    }
  }
  for(int i=0;i<t.nM;i++){
    const int8_t* e=t.expm[i];
    bool L0=(e[1]==0&&e[3]==0), R0=(e[0]==0&&e[2]==0);
    t.mpow[i]=e[4];
    if(L0){ t.mtype[i]=2; t.midx[i]=(int16_t)aidf(t,0,e[0],0,e[2]); }
    else if(R0){ t.mtype[i]=1; t.midx[i]=(int16_t)aidf(t,0,e[1],0,e[3]); }
    else {
      int s=mslot[xidf(t,e[1],e[3])][xidf(t,e[0],e[2])];
      if(s<0) t.err+=1;
      t.mtype[i]=0; t.midx[i]=(int16_t)s;
    }
  }
  for(int i=0;i<t.nB;i++){
    const int8_t* e=t.expb[i];
    t.bcol[i]=(int16_t)aidf(t,0,e[0],0,e[1]); t.bpow[i]=e[2];
  }
  return t;
}

constexpr Tables TB = makeTables();
static_assert(TB.err==0 && TB.gcount==56, "table build failed");
static_assert(TB.nW==120 && TB.nB==20 && TB.nM==56 && TB.nA==35 && TB.nX==10, "enumeration mismatch");

// ---- helpers ----
template<int N, typename F>
DEV void sunroll(F&& f){
  if constexpr (N > 0){
    sunroll<N-1>(static_cast<F&&>(f));
    f(std::integral_constant<int, N-1>{});
  }
}
template<int E> DEV float ipw(float x){
  if constexpr(E==0) return 1.0f;
  else if constexpr(E==1) return x;
  else if constexpr(E==2) return x*x;
  else return x*x*x;
}
DEV u16 f2bf(float f){
  uint32_t u = __builtin_bit_cast(uint32_t, f);
  u = u + 0x7FFFu + ((u>>16)&1u);
  return (u16)(u>>16);
}

// fragment read: lane l, k-block sb, tile t; two 8B reads 128B apart.
// staging mapping: pos = tid*4+j <-> (b = (tid>>8)*16 + ((tid>>4)&3)*4 + j, ch = ((tid>>6)&3)*16 + (tid&15))
DEV bf16x8 readFrag(const u16* lds, int slot, int sb, int t, int l){
  const int base = slot*4096 + ((sb*2 + ((l>>4)>>1))*256 + t*64 + ((l>>4)&1)*32 + (l&15))*4;
  const u16x4 lo = *(const u16x4*)&lds[base];
  const u16x4 hi = *(const u16x4*)&lds[base + 64];
  bf16x8 r;
  r[0]=(short)lo[0]; r[1]=(short)lo[1]; r[2]=(short)lo[2]; r[3]=(short)lo[3];
  r[4]=(short)hi[0]; r[5]=(short)hi[1]; r[6]=(short)hi[2]; r[7]=(short)hi[3];
  return r;
}

// ---- GEMM column: 16 waves, 1 pair (or half-pair) per wave ----
template<int CI>
DEV void colGemm(const float* __restrict__ s1,const float* __restrict__ y1,
                 const float* __restrict__ s2,const float* __restrict__ y2,
                 const float* __restrict__ x1,const float* __restrict__ x2,
                 float* __restrict__ G, u16* lds, int tid, int bi)
{
  constexpr int NS  = TB.col[CI].nslot;
  constexpr int NSP = TB.col[CI].nsplit;
  constexpr int NDB = 4/NSP;
  constexpr int NB  = TB.col[CI].nb;
  constexpr unsigned LM = TB.col[CI].ldmask;

  const int l=tid&63, ob=(tid>>6)&3, sub=tid>>8, w=tid>>6;
  const int ch = ob*16 + (l&15);
  const int bl = sub*16 + ((l>>4)&3)*4;

  int aslot=0,bslot=0,gsl=0,dbase=0;
  sunroll<16>([&](auto W){
    constexpr int ww = decltype(W)::value;
    if(w==ww){
      constexpr int p = ww/NSP;
      aslot = TB.col[CI].pa[p];
      bslot = TB.col[CI].pb[p];
      gsl   = TB.col[CI].gout[p];
      dbase = (ww%NSP)*2;
    }
  });

  const int c0 = (bi*NCHT)/NB, c1 = ((bi+1)*NCHT)/NB;
  f32x4 acc[4][NDB] = {};

  for(int ck=c0; ck<c1; ++ck){
    const int b0 = (ck*KB + bl)*64 + ch;
    float raw[6][4] = {};
    #pragma unroll
    for(int j=0;j<4;j++){
      const int off = b0 + j*64;
      if constexpr(LM&1u)  raw[0][j]=s1[off];
      if constexpr(LM&2u)  raw[1][j]=y1[off];
      if constexpr(LM&4u)  raw[2][j]=s2[off];
      if constexpr(LM&8u)  raw[3][j]=y2[off];
      if constexpr(LM&16u) raw[4][j]=x1[off];
      if constexpr(LM&32u) raw[5][j]=x2[off];
    }
    sunroll<NS>([&](auto S){
      constexpr int s = decltype(S)::value;
      u16x4 o4;
      #pragma unroll
      for(int j=0;j<4;j++){
        float v = ipw<TB.col[CI].sexp[s][0]>(raw[0][j])
                * ipw<TB.col[CI].sexp[s][1]>(raw[1][j])
                * ipw<TB.col[CI].sexp[s][2]>(raw[2][j])
                * ipw<TB.col[CI].sexp[s][3]>(raw[3][j])
                * ipw<TB.col[CI].sexp[s][4]>(raw[4][j])
                * ipw<TB.col[CI].sexp[s][5]>(raw[5][j]);
        o4[j]=f2bf(v);
      }
      *(u16x4*)&lds[s*4096 + tid*4] = o4;
    });
    __syncthreads();
    #pragma unroll
    for(int sb=0; sb<2; ++sb){
      bf16x8 Af[4];
      #pragma unroll
      for(int o2=0;o2<4;o2++) Af[o2]=readFrag(lds,aslot,sb,o2,l);
      #pragma unroll
      for(int dd=0;dd<NDB;dd++){
        bf16x8 Bf=readFrag(lds,bslot,sb,dbase+dd,l);
        #pragma unroll
        for(int o2=0;o2<4;o2++)
          acc[o2][dd]=__builtin_amdgcn_mfma_f32_16x16x32_bf16(Af[o2],Bf,acc[o2][dd],0,0,0);
      }
    }
    __syncthreads();
  }

  float* dst = G + gsl*4096;
  const int r0=(l>>4)*4, cc=l&15;   // C/D layout: col=lane&15, row=(lane>>4)*4+reg
  #pragma unroll
  for(int o2=0;o2<4;o2++)
    #pragma unroll
    for(int dd=0;dd<NDB;dd++)
      #pragma unroll
      for(int r=0;r<4;r++)
        atomicAdd(&dst[(o2*16+r0+r)*64 + (dbase+dd)*16+cc], acc[o2][dd][r]);
}

// ---- reduction column: all 45 colsums in fp32 ----
DEV void colRed(const float* __restrict__ s1,const float* __restrict__ y1,
                const float* __restrict__ s2,const float* __restrict__ y2,
                const float* __restrict__ x1,const float* __restrict__ x2,
                float* __restrict__ col, float* ldsF, int tid, int bi)
{
  const int ch=tid&63, g=tid>>6;
  const int c0=(bi*NCHT)/NBLK_R, c1=((bi+1)*NCHT)/NBLK_R;
  float accv[45];
  sunroll<45>([&](auto K){ accv[decltype(K)::value]=0.f; });
  for(int r=c0*KB+g; r<c1*KB; r+=16){
    const int off=r*64+ch;
    const float v0=s1[off],v1=y1[off],v2=s2[off],v3=y2[off],v4=x1[off],v5=x2[off];
    sunroll<35>([&](auto K){
      constexpr int k=decltype(K)::value;
      accv[k] += ipw<TB.am[k][0]>(v0)*ipw<TB.am[k][1]>(v1)*ipw<TB.am[k][2]>(v2)*ipw<TB.am[k][3]>(v3);
    });
    sunroll<10>([&](auto K){
      constexpr int k=decltype(K)::value;
      accv[35+k] += ipw<TB.xm[k][0]>(v4)*ipw<TB.xm[k][1]>(v5);
    });
  }
  sunroll<5>([&](auto RR){
    constexpr int rr=decltype(RR)::value;
    __syncthreads();
    sunroll<9>([&](auto Q){
      constexpr int q=decltype(Q)::value;
      ldsF[(q*16+g)*64+ch]=accv[rr*9+q];
    });
    __syncthreads();
    if(tid<576){
      const int q=tid>>6, c=tid&63;
      float s=0.f;
      #pragma unroll
      for(int gg=0; gg<16; gg++) s+=ldsF[(q*16+gg)*64+c];
      atomicAdd(&col[(rr*9+q)*64+c], s);
    }
  });
}

__global__ __launch_bounds__(1024) void k_main(
    const float* __restrict__ x1, const float* __restrict__ s1, const float* __restrict__ y1,
    const float* __restrict__ x2, const float* __restrict__ s2, const float* __restrict__ y2,
    float* __restrict__ G, float* __restrict__ col)
{
  __shared__ u16 lds[10*4096];   // 80 KiB
  const int tid = threadIdx.x;
  const int bx = blockIdx.x;
  if      (bx < THR_M)  colGemm<0>(s1,y1,s2,y2,x1,x2,G,lds,tid,bx);
  else if (bx < THR_W1) colGemm<1>(s1,y1,s2,y2,x1,x2,G,lds,tid,bx-THR_M);
  else if (bx < THR_W2) colGemm<2>(s1,y1,s2,y2,x1,x2,G,lds,tid,bx-THR_W1);
  else if (bx < THR_W3) colGemm<3>(s1,y1,s2,y2,x1,x2,G,lds,tid,bx-THR_W2);
  else                  colRed(s1,y1,s2,y2,x1,x2,col,(float*)lds,tid,bx-THR_W3);
}

__global__ __launch_bounds__(256) void k_combine(
    const float* __restrict__ G, const float* __restrict__ col,
    const float* __restrict__ w, const float* __restrict__ b, const float* __restrict__ m,
    const float* __restrict__ parw, const float* __restrict__ parb, const float* __restrict__ parm,
    float* __restrict__ out)
{
  const int n = blockIdx.x*256 + threadIdx.x;   // 0..4095
  const int o = n>>6, d = n&63;
  const float wv = w[n], mv = m[n];
  const float wp[4] = {1.f, wv, wv*wv, wv*wv*wv};
  const float mp[4] = {1.f, mv, mv*mv, mv*mv*mv};
  float aw=0.f, am=0.f;
  sunroll<120>([&](auto II){
    constexpr int i = decltype(II)::value;
    constexpr int ty = TB.wtype[i];
    constexpr int ix = TB.widx[i];
    constexpr int q  = TB.wpow[i];
    float val;
    if constexpr(ty==0) val = G[ix*4096 + n];
    else if constexpr(ty==1) val = col[ix*64 + o];
    else val = col[(35+ix)*64 + d];
    aw += parw[i] * val * wp[q];
  });
  sunroll<56>([&](auto II){
    constexpr int i = decltype(II)::value;
    constexpr int ty = TB.mtype[i];
    constexpr int ix = TB.midx[i];
    constexpr int q  = TB.mpow[i];
    float val;
    if constexpr(ty==0) val = G[ix*4096 + n];
    else if constexpr(ty==1) val = col[ix*64 + o];
    else val = col[ix*64 + d];
    am += parm[i] * val * mp[q];
  });
  aw *= INVB; am *= INVB;
  if (o==d) am += parm[56];
  out[n] = aw;
  out[4160 + n] = am;
  if (n < 64){
    const float bv = b[n];
    const float bp[4] = {1.f, bv, bv*bv, bv*bv*bv};
    float ab=0.f;
    sunroll<20>([&](auto II){
      constexpr int i = decltype(II)::value;
      constexpr int cix = TB.bcol[i];
      constexpr int q = TB.bpow[i];
      ab += parb[i] * col[cix*64 + n] * bp[q];
    });
    out[4096 + n] = ab * INVB;
  }
}

extern "C" void kernel_launch(void* const* d_in, const int* in_sizes, int n_in,
                              void* d_out, int out_size, void* d_ws, size_t ws_size,
                              hipStream_t stream)
{
  const float* x1=(const float*)d_in[0];
  const float* s1=(const float*)d_in[1];
  const float* y1=(const float*)d_in[2];
  const float* x2=(const float*)d_in[3];
  const float* s2=(const float*)d_in[4];
  const float* y2=(const float*)d_in[5];
  const float* w =(const float*)d_in[6];
  const float* b =(const float*)d_in[7];
  const float* m =(const float*)d_in[8];
  const float* parw=(const float*)d_in[9];
  const float* parb=(const float*)d_in[10];
  const float* parm=(const float*)d_in[11];

  float* G   = (float*)d_ws;
  float* col = G + NG*4096;

  hipMemsetAsync(d_ws, 0, (size_t)(NG*4096 + NCOLSUM*64)*sizeof(float), stream);
  k_main<<<GRID, 1024, 0, stream>>>(x1,s1,y1,x2,s2,y2,G,col);
  k_combine<<<16, 256, 0, stream>>>(G,col,w,b,m,parw,parb,parm,(float*)d_out);
}

// Round 4
// 103.622 us; speedup vs baseline: 1.5858x; 1.1959x over previous
//
#include <hip/hip_runtime.h>
#include <type_traits>
#include <stdint.h>

#define DEV __device__ __forceinline__

typedef float f32x4 __attribute__((ext_vector_type(4)));
typedef short bf16x8 __attribute__((ext_vector_type(8)));
typedef unsigned short u16;
typedef u16 u16x4 __attribute__((ext_vector_type(4)));

static constexpr int BTOT = 65536;
static constexpr int KB   = 64;
static constexpr int NCHT = BTOT / KB;      // 1024 total chunks
static constexpr int NG   = 56;             // true GEMM pairs
static constexpr int NCOLSUM = 45;
static constexpr float INVB = 1.0f / (float)BTOT;

// column block counts. GEMM columns halved vs r3 (atomic traffic /2); R backfills.
static constexpr int NBLK_M  = 24;
static constexpr int NBLK_W1 = 48;
static constexpr int NBLK_W2 = 48;
static constexpr int NBLK_W3 = 64;
static constexpr int NBLK_R  = 328;
static constexpr int GRID    = NBLK_M+NBLK_W1+NBLK_W2+NBLK_W3+NBLK_R; // 512
static constexpr int THR_M  = NBLK_M;
static constexpr int THR_W1 = THR_M + NBLK_W1;
static constexpr int THR_W2 = THR_W1 + NBLK_W2;
static constexpr int THR_W3 = THR_W2 + NBLK_W3;

struct Col {
  int nslot, np, nsplit, nb;
  int8_t sexp[10][6];          // slot exps over (s1,y1,s2,y2,x1,x2)
  int8_t pa[16], pb[16];       // pair -> slot indices
  int16_t gout[16];            // pair -> global G slot
  uint8_t ldmask;              // which arrays to load
};

struct Tables {
  int nW, nB, nM, nA, nX;
  int8_t expw[120][7];
  int8_t expb[20][3];
  int8_t expm[56][5];
  int8_t am[35][4];            // 4-var monos (s1,y1,s2,y2), product order
  int8_t xm[10][2];            // 2-var monos, product order
  Col col[4];
  // combine-kernel term tables
  int8_t wtype[120]; int16_t widx[120]; int8_t wpow[120]; // 0:GEMM 1:colA[o] 2:colX[d]
  int8_t mtype[56];  int16_t midx[56];  int8_t mpow[56];  // 0:GEMM 1:colA[o] 2:colA[d]
  int16_t bcol[20];  int8_t bpow[20];
  int err, gcount;
};

constexpr int aidf(const Tables& t,int a,int b,int c,int d){
  for(int i=0;i<t.nA;i++)
    if(t.am[i][0]==a&&t.am[i][1]==b&&t.am[i][2]==c&&t.am[i][3]==d) return i;
  return -1;
}
constexpr int xidf(const Tables& t,int a,int b){
  for(int i=0;i<t.nX;i++) if(t.xm[i][0]==a&&t.xm[i][1]==b) return i;
  return -1;
}

constexpr Tables makeTables(){
  Tables t{};
  t.err = 0;
  // EXP_W (python product order)
  t.nW=0;
  for(int e0=0;e0<4;e0++)for(int e1=0;e1<4;e1++)for(int e2=0;e2<4;e2++)
  for(int e3=0;e3<4;e3++)for(int e4=0;e4<4;e4++)for(int e5=0;e5<4;e5++)
  for(int e6=0;e6<4;e6++) if(e0+e1+e2+e3+e4+e5+e6<=3){
    t.expw[t.nW][0]=(int8_t)e0; t.expw[t.nW][1]=(int8_t)e1; t.expw[t.nW][2]=(int8_t)e2;
    t.expw[t.nW][3]=(int8_t)e3; t.expw[t.nW][4]=(int8_t)e4; t.expw[t.nW][5]=(int8_t)e5;
    t.expw[t.nW][6]=(int8_t)e6; t.nW++;
  }
  t.nB=0;
  for(int e0=0;e0<4;e0++)for(int e1=0;e1<4;e1++)for(int e2=0;e2<4;e2++)
    if(e0+e1+e2<=3){ t.expb[t.nB][0]=(int8_t)e0; t.expb[t.nB][1]=(int8_t)e1; t.expb[t.nB][2]=(int8_t)e2; t.nB++; }
  t.nM=0;
  for(int e0=0;e0<4;e0++)for(int e1=0;e1<4;e1++)for(int e2=0;e2<4;e2++)
  for(int e3=0;e3<4;e3++)for(int e4=0;e4<4;e4++)
    if(e0+e1+e2+e3+e4<=3){
      t.expm[t.nM][0]=(int8_t)e0; t.expm[t.nM][1]=(int8_t)e1; t.expm[t.nM][2]=(int8_t)e2;
      t.expm[t.nM][3]=(int8_t)e3; t.expm[t.nM][4]=(int8_t)e4; t.nM++;
    }
  t.nA=0;
  for(int a=0;a<4;a++)for(int b=0;b<4;b++)for(int c=0;c<4;c++)for(int d=0;d<4;d++)
    if(a+b+c+d<=3){ t.am[t.nA][0]=(int8_t)a; t.am[t.nA][1]=(int8_t)b; t.am[t.nA][2]=(int8_t)c; t.am[t.nA][3]=(int8_t)d; t.nA++; }
  t.nX=0;
  for(int a=0;a<4;a++)for(int b=0;b<4;b++)
    if(a+b<=3){ t.xm[t.nX][0]=(int8_t)a; t.xm[t.nX][1]=(int8_t)b; t.nX++; }

  int wslot[35][10]; int mslot[10][10];
  for(int i=0;i<35;i++)for(int j=0;j<10;j++) wslot[i][j]=-1;
  for(int i=0;i<10;i++)for(int j=0;j<10;j++) mslot[i][j]=-1;

  int slot=0;

  // --- Col 0: M (y-monos of (y1,y2), shared A/B slot set) ---
  {
    Col& c = t.col[0]; c.nslot=5; c.nsplit=1; c.nb=NBLK_M;
    int ye[5][2] = {{0,1},{1,0},{0,2},{1,1},{2,0}};   // (y1e,y2e): y2,y1,y2^2,y1y2,y1^2
    int xmid[5] = {0,0,0,0,0};
    for(int s=0;s<5;s++){
      c.sexp[s][0]=0; c.sexp[s][1]=(int8_t)ye[s][0]; c.sexp[s][2]=0;
      c.sexp[s][3]=(int8_t)ye[s][1]; c.sexp[s][4]=0; c.sexp[s][5]=0;
      xmid[s]=xidf(t, ye[s][0], ye[s][1]);
      if(xmid[s]<0) t.err+=1;
    }
    int p=0;
    for(int L=0;L<2;L++)for(int R=0;R<5;R++){
      c.pa[p]=(int8_t)L; c.pb[p]=(int8_t)R; c.gout[p]=(int16_t)slot;
      mslot[xmid[L]][xmid[R]]=slot; slot++; p++;
    }
    for(int L=2;L<5;L++)for(int R=0;R<2;R++){
      c.pa[p]=(int8_t)L; c.pb[p]=(int8_t)R; c.gout[p]=(int16_t)slot;
      mslot[xmid[L]][xmid[R]]=slot; slot++; p++;
    }
    c.np=p;
    if(p!=16) t.err+=1;
  }
  // --- Col 1/2: W1 (s1,y1) and W2 (s2,y2) ---
  for(int wc=0; wc<2; wc++){
    Col& c = t.col[1+wc]; c.nslot=10; c.nsplit=1; c.nb = wc? NBLK_W2 : NBLK_W1;
    int ae[5][2] = {{1,0},{0,1},{2,0},{1,1},{0,2}};   // (v0e,v1e)
    int xe[5][2] = {{0,1},{1,0},{0,2},{1,1},{2,0}};   // (x1e,x2e)
    int amid[5]={0,0,0,0,0}, xmidb[5]={0,0,0,0,0};
    for(int s=0;s<5;s++){
      for(int q=0;q<6;q++) c.sexp[s][q]=0;
      if(wc==0){ c.sexp[s][0]=(int8_t)ae[s][0]; c.sexp[s][1]=(int8_t)ae[s][1];
                 amid[s]=aidf(t, ae[s][0], ae[s][1], 0, 0); }
      else     { c.sexp[s][2]=(int8_t)ae[s][0]; c.sexp[s][3]=(int8_t)ae[s][1];
                 amid[s]=aidf(t, 0, 0, ae[s][0], ae[s][1]); }
      if(amid[s]<0) t.err+=1;
      for(int q=0;q<6;q++) c.sexp[5+s][q]=0;
      c.sexp[5+s][4]=(int8_t)xe[s][0]; c.sexp[5+s][5]=(int8_t)xe[s][1];
      xmidb[s]=xidf(t, xe[s][0], xe[s][1]);
      if(xmidb[s]<0) t.err+=1;
    }
    int p=0;
    for(int a=0;a<2;a++)for(int b=0;b<5;b++){
      c.pa[p]=(int8_t)a; c.pb[p]=(int8_t)(5+b); c.gout[p]=(int16_t)slot;
      wslot[amid[a]][xmidb[b]]=slot; slot++; p++;
    }
    for(int a=2;a<5;a++)for(int b=0;b<2;b++){
      c.pa[p]=(int8_t)a; c.pb[p]=(int8_t)(5+b); c.gout[p]=(int16_t)slot;
      wslot[amid[a]][xmidb[b]]=slot; slot++; p++;
    }
    c.np=p;
    if(p!=16) t.err+=1;
  }
  // --- Col 3: W3 (mixed deg-2 v's x deg-1 u's), N-split 2 ---
  {
    Col& c = t.col[3]; c.nslot=6; c.nsplit=2; c.nb=NBLK_W3;
    int ae4[4][4] = {{1,0,1,0},{1,0,0,1},{0,1,1,0},{0,1,0,1}};
    int xe[2][2] = {{0,1},{1,0}};
    int amid[4]={0,0,0,0}, xmidb[2]={0,0};
    for(int s=0;s<4;s++){
      c.sexp[s][0]=(int8_t)ae4[s][0]; c.sexp[s][1]=(int8_t)ae4[s][1];
      c.sexp[s][2]=(int8_t)ae4[s][2]; c.sexp[s][3]=(int8_t)ae4[s][3];
      c.sexp[s][4]=0; c.sexp[s][5]=0;
      amid[s]=aidf(t, ae4[s][0], ae4[s][1], ae4[s][2], ae4[s][3]);
      if(amid[s]<0) t.err+=1;
    }
    for(int s=0;s<2;s++){
      for(int q=0;q<6;q++) c.sexp[4+s][q]=0;
      c.sexp[4+s][4]=(int8_t)xe[s][0]; c.sexp[4+s][5]=(int8_t)xe[s][1];
      xmidb[s]=xidf(t, xe[s][0], xe[s][1]);
      if(xmidb[s]<0) t.err+=1;
    }
    int p=0;
    for(int a=0;a<4;a++)for(int b=0;b<2;b++){
      c.pa[p]=(int8_t)a; c.pb[p]=(int8_t)(4+b); c.gout[p]=(int16_t)slot;
      wslot[amid[a]][xmidb[b]]=slot; slot++; p++;
    }
    c.np=p;
    if(p!=8) t.err+=1;
  }
  t.gcount=slot;
  if(slot!=NG) t.err+=1;

  // ldmask from slot exps
  for(int ci=0; ci<4; ci++){
    unsigned m=0;
    for(int s=0;s<t.col[ci].nslot;s++)
      for(int v=0;v<6;v++) if(t.col[ci].sexp[s][v]>0) m |= (1u<<v);
    t.col[ci].ldmask=(uint8_t)m;
  }

  // --- combine tables ---
  for(int i=0;i<t.nW;i++){
    const int8_t* e=t.expw[i];
    bool u0=(e[0]==0&&e[3]==0);
    bool v0=(e[1]==0&&e[2]==0&&e[4]==0&&e[5]==0);
    t.wpow[i]=e[6];
    if(u0){ t.wtype[i]=1; t.widx[i]=(int16_t)aidf(t,e[1],e[2],e[4],e[5]); }
    else if(v0){ t.wtype[i]=2; t.widx[i]=(int16_t)xidf(t,e[0],e[3]); }
    else {
      int s=wslot[aidf(t,e[1],e[2],e[4],e[5])][xidf(t,e[0],e[3])];
      if(s<0) t.err+=1;
      t.wtype[i]=0; t.widx[i]=(int16_t)s;
    }
  }
  for(int i=0;i<t.nM;i++){
    const int8_t* e=t.expm[i];
    bool L0=(e[1]==0&&e[3]==0), R0=(e[0]==0&&e[2]==0);
    t.mpow[i]=e[4];
    if(L0){ t.mtype[i]=2; t.midx[i]=(int16_t)aidf(t,0,e[0],0,e[2]); }
    else if(R0){ t.mtype[i]=1; t.midx[i]=(int16_t)aidf(t,0,e[1],0,e[3]); }
    else {
      int s=mslot[xidf(t,e[1],e[3])][xidf(t,e[0],e[2])];
      if(s<0) t.err+=1;
      t.mtype[i]=0; t.midx[i]=(int16_t)s;
    }
  }
  for(int i=0;i<t.nB;i++){
    const int8_t* e=t.expb[i];
    t.bcol[i]=(int16_t)aidf(t,0,e[0],0,e[1]); t.bpow[i]=e[2];
  }
  return t;
}

constexpr Tables TB = makeTables();
static_assert(TB.err==0 && TB.gcount==56, "table build failed");
static_assert(TB.nW==120 && TB.nB==20 && TB.nM==56 && TB.nA==35 && TB.nX==10, "enumeration mismatch");

// ---- helpers ----
template<int N, typename F>
DEV void sunroll(F&& f){
  if constexpr (N > 0){
    sunroll<N-1>(static_cast<F&&>(f));
    f(std::integral_constant<int, N-1>{});
  }
}
template<int E> DEV float ipw(float x){
  if constexpr(E==0) return 1.0f;
  else if constexpr(E==1) return x;
  else if constexpr(E==2) return x*x;
  else return x*x*x;
}
DEV u16 f2bf(float f){
  uint32_t u = __builtin_bit_cast(uint32_t, f);
  u = u + 0x7FFFu + ((u>>16)&1u);
  return (u16)(u>>16);
}

// fragment read (verified mapping, do not touch): lane l, k-sub sb, tile t.
DEV bf16x8 readFrag(const u16* lds, int slot, int sb, int t, int l){
  const int base = slot*4096 + ((sb*2 + ((l>>4)>>1))*256 + t*64 + ((l>>4)&1)*32 + (l&15))*4;
  const u16x4 lo = *(const u16x4*)&lds[base];
  const u16x4 hi = *(const u16x4*)&lds[base + 64];
  bf16x8 r;
  r[0]=(short)lo[0]; r[1]=(short)lo[1]; r[2]=(short)lo[2]; r[3]=(short)lo[3];
  r[4]=(short)hi[0]; r[5]=(short)hi[1]; r[6]=(short)hi[2]; r[7]=(short)hi[3];
  return r;
}

// ---- GEMM column: 16 waves, reg-prefetch pipelined chunk loop, raw barriers ----
template<int CI>
DEV void colGemm(const float* __restrict__ s1,const float* __restrict__ y1,
                 const float* __restrict__ s2,const float* __restrict__ y2,
                 const float* __restrict__ x1,const float* __restrict__ x2,
                 float* __restrict__ G, u16* lds, int tid, int bi)
{
  constexpr int NS  = TB.col[CI].nslot;
  constexpr int NSP = TB.col[CI].nsplit;
  constexpr int NDB = 4/NSP;
  constexpr int NB  = TB.col[CI].nb;
  constexpr unsigned LM = TB.col[CI].ldmask;

  const int l=tid&63, ob=(tid>>6)&3, sub=tid>>8, w=tid>>6;
  const int ch = ob*16 + (l&15);
  const int bl = sub*16 + ((l>>4)&3)*4;

  int aslot=0,bslot=0,gsl=0,dbase=0;
  sunroll<16>([&](auto W){
    constexpr int ww = decltype(W)::value;
    if(w==ww){
      constexpr int p = ww/NSP;
      aslot = TB.col[CI].pa[p];
      bslot = TB.col[CI].pb[p];
      gsl   = TB.col[CI].gout[p];
      dbase = (ww%NSP)*2;
    }
  });

  const int c0 = (bi*NCHT)/NB, c1 = ((bi+1)*NCHT)/NB;
  f32x4 acc[4][NDB] = {};

  float raw[6][4] = {};
  float nraw[6][4] = {};

  auto issue = [&](int ck, float (&dst)[6][4]){
    const int b0 = (ck*KB + bl)*64 + ch;
    #pragma unroll
    for(int j=0;j<4;j++){
      const int off = b0 + j*64;
      if constexpr(LM&1u)  dst[0][j]=s1[off];
      if constexpr(LM&2u)  dst[1][j]=y1[off];
      if constexpr(LM&4u)  dst[2][j]=s2[off];
      if constexpr(LM&8u)  dst[3][j]=y2[off];
      if constexpr(LM&16u) dst[4][j]=x1[off];
      if constexpr(LM&32u) dst[5][j]=x2[off];
    }
  };

  issue(c0, raw);                       // prologue load

  for(int ck=c0; ck<c1; ++ck){
    // prefetch next chunk into regs (stays in flight across both barriers;
    // drained by the compiler's counted vmcnt at next-iteration staging use)
    const int nk = (ck+1<c1)? ck+1 : c0;
    issue(nk, nraw);

    // stage monomials of current chunk (uses raw -> counted vmcnt here)
    sunroll<NS>([&](auto S){
      constexpr int s = decltype(S)::value;
      u16x4 o4;
      #pragma unroll
      for(int j=0;j<4;j++){
        float v = ipw<TB.col[CI].sexp[s][0]>(raw[0][j])
                * ipw<TB.col[CI].sexp[s][1]>(raw[1][j])
                * ipw<TB.col[CI].sexp[s][2]>(raw[2][j])
                * ipw<TB.col[CI].sexp[s][3]>(raw[3][j])
                * ipw<TB.col[CI].sexp[s][4]>(raw[4][j])
                * ipw<TB.col[CI].sexp[s][5]>(raw[5][j]);
        o4[j]=f2bf(v);
      }
      *(u16x4*)&lds[s*4096 + tid*4] = o4;
    });

    // barrier 1: ds_writes visible to all waves; do NOT drain vmcnt
    asm volatile("s_waitcnt lgkmcnt(0)" ::: "memory");
    __builtin_amdgcn_s_barrier();
    __builtin_amdgcn_sched_barrier(0);

    #pragma unroll
    for(int sb=0; sb<2; ++sb){
      bf16x8 Af[4];
      #pragma unroll
      for(int o2=0;o2<4;o2++) Af[o2]=readFrag(lds,aslot,sb,o2,l);
      #pragma unroll
      for(int dd=0;dd<NDB;dd++){
        bf16x8 Bf=readFrag(lds,bslot,sb,dbase+dd,l);
        #pragma unroll
        for(int o2=0;o2<4;o2++)
          acc[o2][dd]=__builtin_amdgcn_mfma_f32_16x16x32_bf16(Af[o2],Bf,acc[o2][dd],0,0,0);
      }
    }

    // barrier 2: all reads consumed before next staging overwrites LDS
    __builtin_amdgcn_sched_barrier(0);
    __builtin_amdgcn_s_barrier();
    __builtin_amdgcn_sched_barrier(0);

    #pragma unroll
    for(int a=0;a<6;a++)
      #pragma unroll
      for(int j=0;j<4;j++) raw[a][j]=nraw[a][j];
  }

  float* dst = G + gsl*4096;
  const int r0=(l>>4)*4, cc=l&15;   // C/D layout: col=lane&15, row=(lane>>4)*4+reg
  #pragma unroll
  for(int o2=0;o2<4;o2++)
    #pragma unroll
    for(int dd=0;dd<NDB;dd++)
      #pragma unroll
      for(int r=0;r<4;r++)
        atomicAdd(&dst[(o2*16+r0+r)*64 + (dbase+dd)*16+cc], acc[o2][dd][r]);
}

// ---- reduction column: all 45 colsums in fp32 ----
DEV void colRed(const float* __restrict__ s1,const float* __restrict__ y1,
                const float* __restrict__ s2,const float* __restrict__ y2,
                const float* __restrict__ x1,const float* __restrict__ x2,
                float* __restrict__ col, float* ldsF, int tid, int bi)
{
  const int ch=tid&63, g=tid>>6;
  const int c0=(bi*NCHT)/NBLK_R, c1=((bi+1)*NCHT)/NBLK_R;
  float accv[45];
  sunroll<45>([&](auto K){ accv[decltype(K)::value]=0.f; });
  for(int r=c0*KB+g; r<c1*KB; r+=16){
    const int off=r*64+ch;
    const float v0=s1[off],v1=y1[off],v2=s2[off],v3=y2[off],v4=x1[off],v5=x2[off];
    sunroll<35>([&](auto K){
      constexpr int k=decltype(K)::value;
      accv[k] += ipw<TB.am[k][0]>(v0)*ipw<TB.am[k][1]>(v1)*ipw<TB.am[k][2]>(v2)*ipw<TB.am[k][3]>(v3);
    });
    sunroll<10>([&](auto K){
      constexpr int k=decltype(K)::value;
      accv[35+k] += ipw<TB.xm[k][0]>(v4)*ipw<TB.xm[k][1]>(v5);
    });
  }
  sunroll<5>([&](auto RR){
    constexpr int rr=decltype(RR)::value;
    __syncthreads();
    sunroll<9>([&](auto Q){
      constexpr int q=decltype(Q)::value;
      ldsF[(q*16+g)*64+ch]=accv[rr*9+q];
    });
    __syncthreads();
    if(tid<576){
      const int q=tid>>6, c=tid&63;
      float s=0.f;
      #pragma unroll
      for(int gg=0; gg<16; gg++) s+=ldsF[(q*16+gg)*64+c];
      atomicAdd(&col[(rr*9+q)*64+c], s);
    }
  });
}

__global__ __launch_bounds__(1024) void k_main(
    const float* __restrict__ x1, const float* __restrict__ s1, const float* __restrict__ y1,
    const float* __restrict__ x2, const float* __restrict__ s2, const float* __restrict__ y2,
    float* __restrict__ G, float* __restrict__ col)
{
  __shared__ u16 lds[10*4096];   // 80 KiB
  const int tid = threadIdx.x;
  const int bx = blockIdx.x;
  if      (bx < THR_M)  colGemm<0>(s1,y1,s2,y2,x1,x2,G,lds,tid,bx);
  else if (bx < THR_W1) colGemm<1>(s1,y1,s2,y2,x1,x2,G,lds,tid,bx-THR_M);
  else if (bx < THR_W2) colGemm<2>(s1,y1,s2,y2,x1,x2,G,lds,tid,bx-THR_W1);
  else if (bx < THR_W3) colGemm<3>(s1,y1,s2,y2,x1,x2,G,lds,tid,bx-THR_W2);
  else                  colRed(s1,y1,s2,y2,x1,x2,col,(float*)lds,tid,bx-THR_W3);
}

__global__ __launch_bounds__(256) void k_combine(
    const float* __restrict__ G, const float* __restrict__ col,
    const float* __restrict__ w, const float* __restrict__ b, const float* __restrict__ m,
    const float* __restrict__ parw, const float* __restrict__ parb, const float* __restrict__ parm,
    float* __restrict__ out)
{
  const int n = blockIdx.x*256 + threadIdx.x;   // 0..4095
  const int o = n>>6, d = n&63;
  const float wv = w[n], mv = m[n];
  const float wp[4] = {1.f, wv, wv*wv, wv*wv*wv};
  const float mp[4] = {1.f, mv, mv*mv, mv*mv*mv};
  float aw=0.f, am=0.f;
  sunroll<120>([&](auto II){
    constexpr int i = decltype(II)::value;
    constexpr int ty = TB.wtype[i];
    constexpr int ix = TB.widx[i];
    constexpr int q  = TB.wpow[i];
    float val;
    if constexpr(ty==0) val = G[ix*4096 + n];
    else if constexpr(ty==1) val = col[ix*64 + o];
    else val = col[(35+ix)*64 + d];
    aw += parw[i] * val * wp[q];
  });
  sunroll<56>([&](auto II){
    constexpr int i = decltype(II)::value;
    constexpr int ty = TB.mtype[i];
    constexpr int ix = TB.midx[i];
    constexpr int q  = TB.mpow[i];
    float val;
    if constexpr(ty==0) val = G[ix*4096 + n];
    else if constexpr(ty==1) val = col[ix*64 + o];
    else val = col[ix*64 + d];
    am += parm[i] * val * mp[q];
  });
  aw *= INVB; am *= INVB;
  if (o==d) am += parm[56];
  out[n] = aw;
  out[4160 + n] = am;
  if (n < 64){
    const float bv = b[n];
    const float bp[4] = {1.f, bv, bv*bv, bv*bv*bv};
    float ab=0.f;
    sunroll<20>([&](auto II){
      constexpr int i = decltype(II)::value;
      constexpr int cix = TB.bcol[i];
      constexpr int q = TB.bpow[i];
      ab += parb[i] * col[cix*64 + n] * bp[q];
    });
    out[4096 + n] = ab * INVB;
  }
}

extern "C" void kernel_launch(void* const* d_in, const int* in_sizes, int n_in,
                              void* d_out, int out_size, void* d_ws, size_t ws_size,
                              hipStream_t stream)
{
  const float* x1=(const float*)d_in[0];
  const float* s1=(const float*)d_in[1];
  const float* y1=(const float*)d_in[2];
  const float* x2=(const float*)d_in[3];
  const float* s2=(const float*)d_in[4];
  const float* y2=(const float*)d_in[5];
  const float* w =(const float*)d_in[6];
  const float* b =(const float*)d_in[7];
  const float* m =(const float*)d_in[8];
  const float* parw=(const float*)d_in[9];
  const float* parb=(const float*)d_in[10];
  const float* parm=(const float*)d_in[11];

  float* G   = (float*)d_ws;
  float* col = G + NG*4096;

  hipMemsetAsync(d_ws, 0, (size_t)(NG*4096 + NCOLSUM*64)*sizeof(float), stream);
  k_main<<<GRID, 1024, 0, stream>>>(x1,s1,y1,x2,s2,y2,G,col);
  k_combine<<<16, 256, 0, stream>>>(G,col,w,b,m,parw,parb,parm,(float*)d_out);
}